// Round 21
// baseline (300.890 us; speedup 1.0000x reference)
//
#include <hip/hip_runtime.h>
#include <cstdint>

#define N_GRAPHS 20000
#define SCAN_CHUNK 2048
#define NBLK 512  // blocks for bucket hist/scatter
#define SRC_BITS 19  // N=500000 < 2^19; bucket-local dst uses 10 bits

typedef _Float16 half_t;
typedef __attribute__((ext_vector_type(4))) _Float16 half4;
typedef __attribute__((ext_vector_type(8))) _Float16 half8;
typedef __attribute__((ext_vector_type(4))) float f32x4;

// ---------------- prefix scan (exclusive) of in[M] -> out[M+1] ----------------
__global__ __launch_bounds__(256) void scan1(const int* __restrict__ in, int* __restrict__ out,
                                             int* __restrict__ bsum, int M) {
  __shared__ int lds[256];
  int t = threadIdx.x;
  int base = blockIdx.x * SCAN_CHUNK + t * 8;
  int v[8];
  int s = 0;
#pragma unroll
  for (int i = 0; i < 8; ++i) {
    v[i] = (base + i < M) ? in[base + i] : 0;
    s += v[i];
  }
  lds[t] = s;
  __syncthreads();
  for (int off = 1; off < 256; off <<= 1) {
    int x = (t >= off) ? lds[t - off] : 0;
    __syncthreads();
    lds[t] += x;
    __syncthreads();
  }
  if (t == 255) bsum[blockIdx.x] = lds[255];
  int run = (t > 0) ? lds[t - 1] : 0;
#pragma unroll
  for (int i = 0; i < 8; ++i) {
    if (base + i <= M) out[base + i] = run;
    run += v[i];
  }
}

__global__ __launch_bounds__(256) void scan2(int* __restrict__ bsum, int nb) {
  __shared__ int lds[256];
  int t = threadIdx.x;
  lds[t] = (t < nb) ? bsum[t] : 0;
  __syncthreads();
  for (int off = 1; off < 256; off <<= 1) {
    int x = (t >= off) ? lds[t - off] : 0;
    __syncthreads();
    lds[t] += x;
    __syncthreads();
  }
  if (t < nb) bsum[t] = (t > 0) ? lds[t - 1] : 0;  // exclusive
}

__global__ void scan3(int* __restrict__ out, const int* __restrict__ bsum, int Mp1) {
  int i = blockIdx.x * blockDim.x + threadIdx.x;
  if (i < Mp1) out[i] += bsum[i / SCAN_CHUNK];
}

// ---------------- P1: per-block bucket histogram (bucket = dst >> 10) ----------------
__global__ __launch_bounds__(256) void bucket_hist(const int* __restrict__ dst,
                                                   int* __restrict__ bcnt, int E, int nbuck) {
  __shared__ int h[512];
  for (int i = threadIdx.x; i < 512; i += 256) h[i] = 0;
  __syncthreads();
  int per = (E + NBLK - 1) / NBLK;
  int s = blockIdx.x * per;
  int e = min(s + per, E);
  for (int i = s + threadIdx.x; i < e; i += 256) atomicAdd(&h[dst[i] >> 10], 1);
  __syncthreads();
  for (int b = threadIdx.x; b < nbuck; b += 256) bcnt[(long)b * NBLK + blockIdx.x] = h[b];
}

// ------- P2: scatter edges into bucket-ordered packed array: (dst&1023)<<19 | src -------
__global__ __launch_bounds__(256) void bucket_scatter(const int* __restrict__ src,
                                                      const int* __restrict__ dst,
                                                      const int* __restrict__ bbase,
                                                      int* __restrict__ sed, int E, int nbuck) {
  __shared__ int h[512];
  for (int b = threadIdx.x; b < nbuck; b += 256) h[b] = bbase[(long)b * NBLK + blockIdx.x];
  __syncthreads();
  int per = (E + NBLK - 1) / NBLK;
  int s = blockIdx.x * per;
  int e = min(s + per, E);
  for (int i = s + threadIdx.x; i < e; i += 256) {
    int d = dst[i];
    int pos = atomicAdd(&h[d >> 10], 1);
    sed[pos] = ((d & 1023) << SRC_BITS) | src[i];
  }
}

// ----- P3 fused: per-bucket node hist -> rsp (padded start/end) + isq, LDS-rank CSR write,
//       pad slots & sentinel region filled with node index N (zero row) -----
__global__ __launch_bounds__(256) void node_csr(const int* __restrict__ sed,
                                                const int* __restrict__ bbase,
                                                int2* __restrict__ rsp, float* __restrict__ isq,
                                                int* __restrict__ csr, int E, int nbuck, int N,
                                                int PARK) {
  __shared__ int h[1024];
  __shared__ int ws[256];
  __shared__ int cur[1024];
  int b = blockIdx.x;
  int n0 = b << 10;
  int nn = min(1024, N - n0);
  int t = threadIdx.x;
  for (int i = t; i < 1024; i += 256) h[i] = 0;
  __syncthreads();
  int s = bbase[(long)b * NBLK];
  int e = (b + 1 < nbuck) ? bbase[(long)(b + 1) * NBLK] : E;
  for (int i = s + t; i < e; i += 256) atomicAdd(&h[((unsigned)sed[i]) >> SRC_BITS], 1);
  __syncthreads();
  int v0 = h[4 * t], v1 = h[4 * t + 1], v2 = h[4 * t + 2], v3 = h[4 * t + 3];
  int p0 = (v0 + 3) & ~3, p1 = (v1 + 3) & ~3, p2 = (v2 + 3) & ~3, p3 = (v3 + 3) & ~3;
  ws[t] = p0 + p1 + p2 + p3;
  __syncthreads();
  for (int off = 1; off < 256; off <<= 1) {
    int x = (t >= off) ? ws[t - off] : 0;
    __syncthreads();
    ws[t] += x;
    __syncthreads();
  }
  int pbase = s + 3072 * b;
  int st0 = pbase + ((t > 0) ? ws[t - 1] : 0);
  int st1 = st0 + p0, st2 = st1 + p1, st3 = st2 + p2;
  int i0 = 4 * t;
  cur[i0] = st0;
  cur[i0 + 1] = st1;
  cur[i0 + 2] = st2;
  cur[i0 + 3] = st3;
  if (i0 < nn) { rsp[n0 + i0] = make_int2(st0, st0 + p0); isq[n0 + i0] = rsqrtf((float)(v0 + 1)); }
  if (i0 + 1 < nn) { rsp[n0 + i0 + 1] = make_int2(st1, st1 + p1); isq[n0 + i0 + 1] = rsqrtf((float)(v1 + 1)); }
  if (i0 + 2 < nn) { rsp[n0 + i0 + 2] = make_int2(st2, st2 + p2); isq[n0 + i0 + 2] = rsqrtf((float)(v2 + 1)); }
  if (i0 + 3 < nn) { rsp[n0 + i0 + 3] = make_int2(st3, st3 + p3); isq[n0 + i0 + 3] = rsqrtf((float)(v3 + 1)); }
  __syncthreads();
  // rank + write csr
  for (int i = s + t; i < e; i += 256) {
    int v = sed[i];
    int pos = atomicAdd(&cur[((unsigned)v) >> SRC_BITS], 1);
    csr[pos] = v & ((1 << SRC_BITS) - 1);
  }
  __syncthreads();
  // fill pad slots with sentinel N (zero row)
  for (int j = v0; j < p0; ++j) csr[st0 + j] = N;
  for (int j = v1; j < p1; ++j) csr[st1 + j] = N;
  for (int j = v2; j < p2; ++j) csr[st2 + j] = N;
  for (int j = v3; j < p3; ++j) csr[st3 + j] = N;
  if (b == 0 && t < 64) csr[PARK + t] = N;  // parking region
}

// ------- degree-bin counting sort: perm = node ids ordered by gather iteration count -------
__global__ __launch_bounds__(256) void bin_hist(const int2* __restrict__ rsp,
                                                int* __restrict__ bcnt2, int N) {
  __shared__ int h[16];
  if (threadIdx.x < 16) h[threadIdx.x] = 0;
  __syncthreads();
  int per = (N + NBLK - 1) / NBLK;
  int s = blockIdx.x * per;
  int e = min(s + per, N);
  for (int i = s + threadIdx.x; i < e; i += 256) {
    int2 rr = rsp[i];
    int it = (rr.y - rr.x) >> 2;
    atomicAdd(&h[min(it, 15)], 1);
  }
  __syncthreads();
  if (threadIdx.x < 16) bcnt2[(long)threadIdx.x * NBLK + blockIdx.x] = h[threadIdx.x];
}

__global__ __launch_bounds__(256) void bin_scatter(const int2* __restrict__ rsp,
                                                   const int* __restrict__ bbase2,
                                                   int* __restrict__ perm, int N) {
  __shared__ int h[16];
  if (threadIdx.x < 16) h[threadIdx.x] = bbase2[(long)threadIdx.x * NBLK + blockIdx.x];
  __syncthreads();
  int per = (N + NBLK - 1) / NBLK;
  int s = blockIdx.x * per;
  int e = min(s + per, N);
  for (int i = s + threadIdx.x; i < e; i += 256) {
    int2 rr = rsp[i];
    int it = (rr.y - rr.x) >> 2;
    int pos = atomicAdd(&h[min(it, 15)], 1);
    perm[pos] = i;
  }
}

// ------- scale+cast: xs1[n,:] = half(x[n,:] * isq[n]); also zero sentinel rows -------
__global__ __launch_bounds__(256) void scale_cast(const float* __restrict__ x,
                                                  const float* __restrict__ isq,
                                                  half_t* __restrict__ xs1,
                                                  half_t* __restrict__ xs2,
                                                  long nocts, int N) {
  long i = (long)blockIdx.x * 256 + threadIdx.x;
  if (blockIdx.x == 0 && threadIdx.x < 16) {  // zero sentinel row N of both buffers
    const half8 z = {(half_t)0, (half_t)0, (half_t)0, (half_t)0,
                     (half_t)0, (half_t)0, (half_t)0, (half_t)0};
    half_t* base = (threadIdx.x < 8) ? xs1 : xs2;
    ((half8*)(base + (size_t)N * 64))[threadIdx.x & 7] = z;
  }
  if (i >= nocts) return;
  int node = (int)(i >> 3);
  float s = isq[node];
  float4 vlo = ((const float4*)x)[i * 2];
  float4 vhi = ((const float4*)x)[i * 2 + 1];
  half8 h;
  h[0] = (half_t)(vlo.x * s);
  h[1] = (half_t)(vlo.y * s);
  h[2] = (half_t)(vlo.z * s);
  h[3] = (half_t)(vlo.w * s);
  h[4] = (half_t)(vhi.x * s);
  h[5] = (half_t)(vhi.y * s);
  h[6] = (half_t)(vhi.z * s);
  h[7] = (half_t)(vhi.w * s);
  ((half8*)xs1)[i] = h;
}

// ------- fused gather conv with MFMA epilogue, degree-sorted node order -------
__global__ __launch_bounds__(256) void gather_fused(const half_t* __restrict__ xs,
                                                    const int* __restrict__ csr,
                                                    const int2* __restrict__ rsp,
                                                    const float* __restrict__ isq,
                                                    const int* __restrict__ perm,
                                                    const float* __restrict__ W,
                                                    const float* __restrict__ bias,
                                                    half_t* __restrict__ out, int N,
                                                    int PARK, int scale_out) {
  __shared__ half_t Wt[64][72];   // [c][k] fp16 transposed (B-fragment contiguous)
  __shared__ half_t exh[32][72];  // [slot][k] fp16 agg (A-fragment contiguous)
  __shared__ float idv[32];
  __shared__ int pnv[32];         // true node id per slot (-1 = invalid)
  int tid = threadIdx.x;
  {
    int c = tid & 63;
    int kb = (tid >> 6) * 16;
#pragma unroll
    for (int i = 0; i < 16; ++i) Wt[c][kb + i] = (half_t)W[(kb + i) * 64 + c];
  }

  int lane = tid & 63;
  int sub = lane & 7;
  int grp = lane >> 3;
  int li = tid >> 3;
  int wid = (blockIdx.x * blockDim.x + tid) >> 6;
  long i0 = (long)wid * 8;
  long idx = i0 + grp;
  bool vd = (i0 < N) && (idx < N);
  int dd = vd ? perm[idx] : (N - 1);
  int2 rr = rsp[dd];
  int jj = vd ? rr.x : PARK;
  int je = vd ? rr.y : PARK;
  float id = isq[dd];
  const uint8_t* xb = (const uint8_t*)xs;
  uint32_t co = (uint32_t)sub << 4;
  float ac[8];
  {
    half8 sv = *(const half8*)(xb + (((uint32_t)dd << 7) + co));
#pragma unroll
    for (int c = 0; c < 8; ++c) ac[c] = (float)sv[c];
  }
  jj = (jj < je) ? jj : PARK;
  while (__any(jj != PARK)) {
    int s0 = csr[jj];
    int s1 = csr[jj + 1];
    int s2 = csr[jj + 2];
    int s3 = csr[jj + 3];
    half8 v0 = *(const half8*)(xb + (((uint32_t)s0 << 7) + co));
    half8 v1 = *(const half8*)(xb + (((uint32_t)s1 << 7) + co));
    half8 v2 = *(const half8*)(xb + (((uint32_t)s2 << 7) + co));
    half8 v3 = *(const half8*)(xb + (((uint32_t)s3 << 7) + co));
    half8 sum = (v0 + v1) + (v2 + v3);
#pragma unroll
    for (int c = 0; c < 8; ++c) ac[c] += (float)sum[c];
    jj += 4;
    jj = (jj < je) ? jj : PARK;
  }
  {
    half8 ah;
#pragma unroll
    for (int c = 0; c < 8; ++c) ah[c] = (half_t)ac[c];
    *(half8*)&exh[li][sub * 8] = ah;
    if (sub == 0) {
      idv[li] = id;
      pnv[li] = vd ? dd : -1;
    }
  }
  __syncthreads();

  int w = tid >> 6;
  int lr = lane & 15;
  int lk = lane >> 4;
#pragma unroll
  for (int t2 = 0; t2 < 2; ++t2) {
    int tile = w * 2 + t2;
    int mt = tile >> 2;
    int nt = tile & 3;
    f32x4 acc = {0.f, 0.f, 0.f, 0.f};
#pragma unroll
    for (int ks = 0; ks < 2; ++ks) {
      half8 a = *(const half8*)&exh[mt * 16 + lr][ks * 32 + lk * 8];
      half8 b = *(const half8*)&Wt[nt * 16 + lr][ks * 32 + lk * 8];
      acc = __builtin_amdgcn_mfma_f32_16x16x32_f16(a, b, acc, 0, 0, 0);
    }
    float bv = bias[nt * 16 + lr];
#pragma unroll
    for (int j = 0; j < 4; ++j) {
      int nl = mt * 16 + lk * 4 + j;
      int pn = pnv[nl];
      if (pn >= 0) {
        float id2 = idv[nl];
        float m = scale_out ? id2 : 1.f;
        float r = fmaxf(fmaf(acc[j], id2, bv), 0.f) * m;
        out[(long)pn * 64 + nt * 16 + lr] = (half_t)r;
      }
    }
  }
}

// ---------------- graph segment offsets from sorted batch_idx ----------------
__global__ void seg_offsets(const int* __restrict__ batch, int* __restrict__ off, int N, int G) {
  int i = blockIdx.x * blockDim.x + threadIdx.x;
  if (i >= N) return;
  int b = batch[i];
  if (i == 0) {
    for (int g = 0; g <= b; ++g) off[g] = 0;
  } else {
    int pb = batch[i - 1];
    for (int g = pb + 1; g <= b; ++g) off[g] = i;
  }
  if (i == N - 1) {
    for (int g = b + 1; g <= G; ++g) off[g] = N;
  }
}

// ------- mean pool over fp16 rows: lane = half8 (16B), 8 row-parities/wave -------
__global__ void pool_mean(const half_t* __restrict__ e2, const int* __restrict__ off,
                          float* __restrict__ ge, int G) {
  int lane = threadIdx.x & 63;
  int wid = (blockIdx.x * blockDim.x + threadIdx.x) >> 6;
  int nw = (gridDim.x * blockDim.x) >> 6;
  int c8 = lane & 7;
  int rp = lane >> 3;
  for (int g = wid; g < G; g += nw) {
    int s = off[g];
    int e = off[g + 1];
    float acc[8];
#pragma unroll
    for (int c = 0; c < 8; ++c) acc[c] = 0.f;
    for (int n = s + rp; n < e; n += 8) {
      half8 v = *(const half8*)&e2[(long)n * 64 + c8 * 8];
#pragma unroll
      for (int c = 0; c < 8; ++c) acc[c] += (float)v[c];
    }
#pragma unroll
    for (int c = 0; c < 8; ++c) {
      acc[c] += __shfl_xor(acc[c], 8, 64);
      acc[c] += __shfl_xor(acc[c], 16, 64);
      acc[c] += __shfl_xor(acc[c], 32, 64);
    }
    if (rp == 0) {
      float inv = 1.f / fmaxf((float)(e - s), 1.f);
      float4 lo = make_float4(acc[0] * inv, acc[1] * inv, acc[2] * inv, acc[3] * inv);
      float4 hi = make_float4(acc[4] * inv, acc[5] * inv, acc[6] * inv, acc[7] * inv);
      *(float4*)&ge[(long)g * 64 + c8 * 8] = lo;
      *(float4*)&ge[(long)g * 64 + c8 * 8 + 4] = hi;
    }
  }
}

// ------- pair MLP via MFMA: 256 pairs/block; feat & Wr1^T staged fp16 in LDS -------
#define PPB 256
__global__ __launch_bounds__(256) void pair_mlp(const float* __restrict__ ge,
                                                const int* __restrict__ dp,
                                                const float* __restrict__ Wr1,
                                                const float* __restrict__ br1,
                                                const float* __restrict__ Wr2,
                                                const float* __restrict__ br2,
                                                float* __restrict__ out, int P) {
  __shared__ half_t Wt[256][136];  // [hidden j][k] fp16 (~69.6 KB)
  __shared__ half_t ft[PPB][136];  // [pair][k] fp16 (~69.6 KB)
  int tid = threadIdx.x;
  for (int idx = tid; idx < 128 * 256; idx += 256) {
    int k = idx >> 8;
    int j = idx & 255;
    Wt[j][k] = (half_t)Wr1[idx];
  }
  int base = blockIdx.x * PPB;
  {
    int pp = base + tid;
    bool v = pp < P;
    int ga = v ? dp[pp] : 0;
    int gb = v ? dp[P + pp] : 0;
#pragma unroll
    for (int h = 0; h < 8; ++h) {
      const float* srow = (h < 4) ? &ge[(long)ga * 64 + h * 16] : &ge[(long)gb * 64 + (h - 4) * 16];
      float4 a0 = *(const float4*)&srow[0];
      float4 a1 = *(const float4*)&srow[4];
      float4 a2 = *(const float4*)&srow[8];
      float4 a3 = *(const float4*)&srow[12];
      half8 h0, h1;
      h0[0] = (half_t)a0.x; h0[1] = (half_t)a0.y; h0[2] = (half_t)a0.z; h0[3] = (half_t)a0.w;
      h0[4] = (half_t)a1.x; h0[5] = (half_t)a1.y; h0[6] = (half_t)a1.z; h0[7] = (half_t)a1.w;
      h1[0] = (half_t)a2.x; h1[1] = (half_t)a2.y; h1[2] = (half_t)a2.z; h1[3] = (half_t)a2.w;
      h1[4] = (half_t)a3.x; h1[5] = (half_t)a3.y; h1[6] = (half_t)a3.z; h1[7] = (half_t)a3.w;
      *(half8*)&ft[tid][h * 16] = h0;
      *(half8*)&ft[tid][h * 16 + 8] = h1;
    }
  }
  __syncthreads();

  int w = tid >> 6;
  int lane = tid & 63;
  int lr = lane & 15;
  int lk = lane >> 4;
  float b1v[16], w2v[16];
#pragma unroll
  for (int nt = 0; nt < 16; ++nt) {
    b1v[nt] = br1[nt * 16 + lr];
    w2v[nt] = Wr2[nt * 16 + lr];
  }
  float br2v = br2[0];
#pragma unroll
  for (int m4 = 0; m4 < 4; ++m4) {
    int mt = w * 4 + m4;
    float ps0 = 0.f, ps1 = 0.f, ps2 = 0.f, ps3 = 0.f;
#pragma unroll
    for (int nt = 0; nt < 16; ++nt) {
      f32x4 acc = {0.f, 0.f, 0.f, 0.f};
#pragma unroll
      for (int ks = 0; ks < 4; ++ks) {
        half8 a = *(const half8*)&ft[mt * 16 + lr][ks * 32 + lk * 8];
        half8 b = *(const half8*)&Wt[nt * 16 + lr][ks * 32 + lk * 8];
        acc = __builtin_amdgcn_mfma_f32_16x16x32_f16(a, b, acc, 0, 0, 0);
      }
      ps0 += fmaxf(acc[0] + b1v[nt], 0.f) * w2v[nt];
      ps1 += fmaxf(acc[1] + b1v[nt], 0.f) * w2v[nt];
      ps2 += fmaxf(acc[2] + b1v[nt], 0.f) * w2v[nt];
      ps3 += fmaxf(acc[3] + b1v[nt], 0.f) * w2v[nt];
    }
#pragma unroll
    for (int o = 1; o < 16; o <<= 1) {
      ps0 += __shfl_xor(ps0, o, 64);
      ps1 += __shfl_xor(ps1, o, 64);
      ps2 += __shfl_xor(ps2, o, 64);
      ps3 += __shfl_xor(ps3, o, 64);
    }
    if (lr == 0) {
      int prow = mt * 16 + lk * 4;
      int pp = base + prow;
      if (pp + 0 < P) out[pp + 0] = ps0 + br2v;
      if (pp + 1 < P) out[pp + 1] = ps1 + br2v;
      if (pp + 2 < P) out[pp + 2] = ps2 + br2v;
      if (pp + 3 < P) out[pp + 3] = ps3 + br2v;
    }
  }
}

extern "C" void kernel_launch(void* const* d_in, const int* in_sizes, int n_in,
                              void* d_out, int out_size, void* d_ws, size_t ws_size,
                              hipStream_t stream) {
  const float* x = (const float*)d_in[0];
  const int* ei = (const int*)d_in[1];
  const int* batch = (const int*)d_in[2];
  const int* dp = (const int*)d_in[3];
  const float* W1 = (const float*)d_in[4];
  const float* b1 = (const float*)d_in[5];
  const float* W2 = (const float*)d_in[6];
  const float* b2 = (const float*)d_in[7];
  const float* Wr1 = (const float*)d_in[8];
  const float* br1 = (const float*)d_in[9];
  const float* Wr2 = (const float*)d_in[10];
  const float* br2 = (const float*)d_in[11];
  float* out = (float*)d_out;

  int N = in_sizes[0] / 64;
  int E = in_sizes[1] / 2;
  int P = in_sizes[3] / 2;
  int G = N_GRAPHS;
  const int* src = ei;
  const int* dstp = ei + E;

  int nbuck = (N + 1023) >> 10;  // <= 512
  long M = (long)nbuck * NBLK;
  long M2 = 16L * NBLK;          // degree-bin matrix
  int PARK = E + 3072 * nbuck;   // start of parking region in padded csr space

  char* ws = (char*)d_ws;
  size_t o = 0;
  auto alloc = [&](size_t bytes) {
    void* p = ws + o;
    o += (bytes + 255) & ~(size_t)255;
    return p;
  };
  float* isq = (float*)alloc((size_t)N * 4);
  int2* rsp = (int2*)alloc((size_t)N * 8);
  int* perm = (int*)alloc((size_t)N * 4);
  int* bsum = (int*)alloc(1024 * 4);
  int* goff = (int*)alloc((size_t)(G + 1) * 4);
  int* bcnt = (int*)alloc((size_t)(M + 1) * 4);
  int* bcnt2 = (int*)alloc((size_t)(M2 + 1) * 4);
  int* sed = (int*)alloc((size_t)E * 4);
  int* csr = (int*)alloc((size_t)(PARK + 80) * 4);
  half_t* xs1 = (half_t*)alloc((size_t)(N + 1) * 64 * 2);
  half_t* xs2 = (half_t*)alloc((size_t)(N + 1) * 64 * 2);
  half_t* abuf = (half_t*)alloc((size_t)N * 64 * 2);
  float* ge = (float*)alloc((size_t)G * 64 * 4);

  // --- CSR build, atomic-free at global scope ---
  bucket_hist<<<NBLK, 256, 0, stream>>>(dstp, bcnt, E, nbuck);
  int nbA = (int)((M + SCAN_CHUNK - 1) / SCAN_CHUNK);
  scan1<<<nbA, 256, 0, stream>>>(bcnt, bcnt, bsum, (int)M);
  scan2<<<1, 256, 0, stream>>>(bsum, nbA);
  scan3<<<(int)((M + 1 + 255) / 256), 256, 0, stream>>>(bcnt, bsum, (int)(M + 1));
  bucket_scatter<<<NBLK, 256, 0, stream>>>(src, dstp, bcnt, sed, E, nbuck);
  node_csr<<<nbuck, 256, 0, stream>>>(sed, bcnt, rsp, isq, csr, E, nbuck, N, PARK);
  // --- degree-sort nodes by gather iteration count ---
  bin_hist<<<NBLK, 256, 0, stream>>>(rsp, bcnt2, N);
  int nbB = (int)((M2 + SCAN_CHUNK - 1) / SCAN_CHUNK);  // 4
  scan1<<<nbB, 256, 0, stream>>>(bcnt2, bcnt2, bsum, (int)M2);
  scan2<<<1, 256, 0, stream>>>(bsum, nbB);
  scan3<<<(int)((M2 + 1 + 255) / 256), 256, 0, stream>>>(bcnt2, bsum, (int)(M2 + 1));
  bin_scatter<<<NBLK, 256, 0, stream>>>(rsp, bcnt2, perm, N);
  seg_offsets<<<(N + 255) / 256, 256, 0, stream>>>(batch, goff, N, G);

  long nocts = (long)N * 8;
  int gblocks = (N + 31) / 32;
  // xs1 = x * isq (fp16); also zeroes sentinel rows of xs1/xs2
  scale_cast<<<(int)((nocts + 255) / 256), 256, 0, stream>>>(x, isq, xs1, xs2, nocts, N);
  // conv1: gather xs1 (degree-sorted), MFMA @W1 epilogue, out xs2 = relu1*isq (fp16)
  gather_fused<<<gblocks, 256, 0, stream>>>(xs1, csr, rsp, isq, perm, W1, b1, xs2, N, PARK, 1);
  // conv2: gather xs2 (degree-sorted), MFMA @W2 epilogue, out abuf = relu2 (fp16)
  gather_fused<<<gblocks, 256, 0, stream>>>(xs2, csr, rsp, isq, perm, W2, b2, abuf, N, PARK, 0);
  // pool
  pool_mean<<<2048, 256, 0, stream>>>(abuf, goff, ge, G);
  // pair MLP (MFMA)
  pair_mlp<<<(P + PPB - 1) / PPB, 256, 0, stream>>>(ge, dp, Wr1, br1, Wr2, br2, out, P);
}

// Round 22
// 275.468 us; speedup vs baseline: 1.0923x; 1.0923x over previous
//
#include <hip/hip_runtime.h>
#include <cstdint>

#define N_GRAPHS 20000
#define SCAN_CHUNK 2048
#define NBLK 512  // blocks for bucket hist/scatter
#define SRC_BITS 19  // N=500000 < 2^19; bucket-local dst uses 10 bits

typedef _Float16 half_t;
typedef __attribute__((ext_vector_type(4))) _Float16 half4;
typedef __attribute__((ext_vector_type(8))) _Float16 half8;
typedef __attribute__((ext_vector_type(4))) float f32x4;

// ---------------- prefix scan (exclusive) of in[M] -> out[M+1] ----------------
__global__ __launch_bounds__(256) void scan1(const int* __restrict__ in, int* __restrict__ out,
                                             int* __restrict__ bsum, int M) {
  __shared__ int lds[256];
  int t = threadIdx.x;
  int base = blockIdx.x * SCAN_CHUNK + t * 8;
  int v[8];
  int s = 0;
#pragma unroll
  for (int i = 0; i < 8; ++i) {
    v[i] = (base + i < M) ? in[base + i] : 0;
    s += v[i];
  }
  lds[t] = s;
  __syncthreads();
  for (int off = 1; off < 256; off <<= 1) {
    int x = (t >= off) ? lds[t - off] : 0;
    __syncthreads();
    lds[t] += x;
    __syncthreads();
  }
  if (t == 255) bsum[blockIdx.x] = lds[255];
  int run = (t > 0) ? lds[t - 1] : 0;
#pragma unroll
  for (int i = 0; i < 8; ++i) {
    if (base + i <= M) out[base + i] = run;
    run += v[i];
  }
}

__global__ __launch_bounds__(256) void scan2(int* __restrict__ bsum, int nb) {
  __shared__ int lds[256];
  int t = threadIdx.x;
  lds[t] = (t < nb) ? bsum[t] : 0;
  __syncthreads();
  for (int off = 1; off < 256; off <<= 1) {
    int x = (t >= off) ? lds[t - off] : 0;
    __syncthreads();
    lds[t] += x;
    __syncthreads();
  }
  if (t < nb) bsum[t] = (t > 0) ? lds[t - 1] : 0;  // exclusive
}

__global__ void scan3(int* __restrict__ out, const int* __restrict__ bsum, int Mp1) {
  int i = blockIdx.x * blockDim.x + threadIdx.x;
  if (i < Mp1) out[i] += bsum[i / SCAN_CHUNK];
}

// ---------------- P1: per-block bucket histogram (bucket = dst >> 10) ----------------
__global__ __launch_bounds__(256) void bucket_hist(const int* __restrict__ dst,
                                                   int* __restrict__ bcnt, int E, int nbuck) {
  __shared__ int h[512];
  for (int i = threadIdx.x; i < 512; i += 256) h[i] = 0;
  __syncthreads();
  int per = (E + NBLK - 1) / NBLK;
  int s = blockIdx.x * per;
  int e = min(s + per, E);
  for (int i = s + threadIdx.x; i < e; i += 256) atomicAdd(&h[dst[i] >> 10], 1);
  __syncthreads();
  for (int b = threadIdx.x; b < nbuck; b += 256) bcnt[(long)b * NBLK + blockIdx.x] = h[b];
}

// ------- P2: scatter edges into bucket-ordered packed array: (dst&1023)<<19 | src -------
__global__ __launch_bounds__(256) void bucket_scatter(const int* __restrict__ src,
                                                      const int* __restrict__ dst,
                                                      const int* __restrict__ bbase,
                                                      int* __restrict__ sed, int E, int nbuck) {
  __shared__ int h[512];
  for (int b = threadIdx.x; b < nbuck; b += 256) h[b] = bbase[(long)b * NBLK + blockIdx.x];
  __syncthreads();
  int per = (E + NBLK - 1) / NBLK;
  int s = blockIdx.x * per;
  int e = min(s + per, E);
  for (int i = s + threadIdx.x; i < e; i += 256) {
    int d = dst[i];
    int pos = atomicAdd(&h[d >> 10], 1);
    sed[pos] = ((d & 1023) << SRC_BITS) | src[i];
  }
}

// ----- P3 fused: per-bucket node hist -> rsp (padded start/end) + isq, LDS-rank CSR write,
//       pad slots & sentinel region filled with node index N (zero row) -----
__global__ __launch_bounds__(256) void node_csr(const int* __restrict__ sed,
                                                const int* __restrict__ bbase,
                                                int2* __restrict__ rsp, float* __restrict__ isq,
                                                int* __restrict__ csr, int E, int nbuck, int N,
                                                int PARK) {
  __shared__ int h[1024];
  __shared__ int ws[256];
  __shared__ int cur[1024];
  int b = blockIdx.x;
  int n0 = b << 10;
  int nn = min(1024, N - n0);
  int t = threadIdx.x;
  for (int i = t; i < 1024; i += 256) h[i] = 0;
  __syncthreads();
  int s = bbase[(long)b * NBLK];
  int e = (b + 1 < nbuck) ? bbase[(long)(b + 1) * NBLK] : E;
  for (int i = s + t; i < e; i += 256) atomicAdd(&h[((unsigned)sed[i]) >> SRC_BITS], 1);
  __syncthreads();
  int v0 = h[4 * t], v1 = h[4 * t + 1], v2 = h[4 * t + 2], v3 = h[4 * t + 3];
  int p0 = (v0 + 3) & ~3, p1 = (v1 + 3) & ~3, p2 = (v2 + 3) & ~3, p3 = (v3 + 3) & ~3;
  ws[t] = p0 + p1 + p2 + p3;
  __syncthreads();
  for (int off = 1; off < 256; off <<= 1) {
    int x = (t >= off) ? ws[t - off] : 0;
    __syncthreads();
    ws[t] += x;
    __syncthreads();
  }
  int pbase = s + 3072 * b;
  int st0 = pbase + ((t > 0) ? ws[t - 1] : 0);
  int st1 = st0 + p0, st2 = st1 + p1, st3 = st2 + p2;
  int i0 = 4 * t;
  cur[i0] = st0;
  cur[i0 + 1] = st1;
  cur[i0 + 2] = st2;
  cur[i0 + 3] = st3;
  if (i0 < nn) { rsp[n0 + i0] = make_int2(st0, st0 + p0); isq[n0 + i0] = rsqrtf((float)(v0 + 1)); }
  if (i0 + 1 < nn) { rsp[n0 + i0 + 1] = make_int2(st1, st1 + p1); isq[n0 + i0 + 1] = rsqrtf((float)(v1 + 1)); }
  if (i0 + 2 < nn) { rsp[n0 + i0 + 2] = make_int2(st2, st2 + p2); isq[n0 + i0 + 2] = rsqrtf((float)(v2 + 1)); }
  if (i0 + 3 < nn) { rsp[n0 + i0 + 3] = make_int2(st3, st3 + p3); isq[n0 + i0 + 3] = rsqrtf((float)(v3 + 1)); }
  __syncthreads();
  // rank + write csr
  for (int i = s + t; i < e; i += 256) {
    int v = sed[i];
    int pos = atomicAdd(&cur[((unsigned)v) >> SRC_BITS], 1);
    csr[pos] = v & ((1 << SRC_BITS) - 1);
  }
  __syncthreads();
  // fill pad slots with sentinel N (zero row)
  for (int j = v0; j < p0; ++j) csr[st0 + j] = N;
  for (int j = v1; j < p1; ++j) csr[st1 + j] = N;
  for (int j = v2; j < p2; ++j) csr[st2 + j] = N;
  for (int j = v3; j < p3; ++j) csr[st3 + j] = N;
  if (b == 0 && t < 64) csr[PARK + t] = N;  // parking region
}

// ------- scale+cast: xs1[n,:] = half(x[n,:] * isq[n]); also zero sentinel rows -------
__global__ __launch_bounds__(256) void scale_cast(const float* __restrict__ x,
                                                  const float* __restrict__ isq,
                                                  half_t* __restrict__ xs1,
                                                  half_t* __restrict__ xs2,
                                                  long nocts, int N) {
  long i = (long)blockIdx.x * 256 + threadIdx.x;
  if (blockIdx.x == 0 && threadIdx.x < 16) {  // zero sentinel row N of both buffers
    const half8 z = {(half_t)0, (half_t)0, (half_t)0, (half_t)0,
                     (half_t)0, (half_t)0, (half_t)0, (half_t)0};
    half_t* base = (threadIdx.x < 8) ? xs1 : xs2;
    ((half8*)(base + (size_t)N * 64))[threadIdx.x & 7] = z;
  }
  if (i >= nocts) return;
  int node = (int)(i >> 3);
  float s = isq[node];
  float4 vlo = ((const float4*)x)[i * 2];
  float4 vhi = ((const float4*)x)[i * 2 + 1];
  half8 h;
  h[0] = (half_t)(vlo.x * s);
  h[1] = (half_t)(vlo.y * s);
  h[2] = (half_t)(vlo.z * s);
  h[3] = (half_t)(vlo.w * s);
  h[4] = (half_t)(vhi.x * s);
  h[5] = (half_t)(vhi.y * s);
  h[6] = (half_t)(vhi.z * s);
  h[7] = (half_t)(vhi.w * s);
  ((half8*)xs1)[i] = h;
}

// ------- fused gather conv with MFMA epilogue -------
__global__ __launch_bounds__(256) void gather_fused(const half_t* __restrict__ xs,
                                                    const int* __restrict__ csr,
                                                    const int2* __restrict__ rsp,
                                                    const float* __restrict__ isq,
                                                    const float* __restrict__ W,
                                                    const float* __restrict__ bias,
                                                    half_t* __restrict__ out, int N,
                                                    int PARK, int scale_out) {
  __shared__ half_t Wt[64][72];   // [c][k] fp16 transposed (B-fragment contiguous)
  __shared__ half_t exh[32][72];  // [node][k] fp16 agg (A-fragment contiguous)
  __shared__ float idv[32];
  int tid = threadIdx.x;
  {
    int c = tid & 63;
    int kb = (tid >> 6) * 16;
#pragma unroll
    for (int i = 0; i < 16; ++i) Wt[c][kb + i] = (half_t)W[(kb + i) * 64 + c];
  }

  int lane = tid & 63;
  int sub = lane & 7;
  int grp = lane >> 3;
  int li = tid >> 3;
  int wid = (blockIdx.x * blockDim.x + tid) >> 6;
  long d0 = (long)wid * 8;
  int d = (int)d0 + grp;
  bool vd = (d0 < N) && (d < N);
  int dd = vd ? d : N - 1;
  int2 rr = rsp[dd];
  int jj = vd ? rr.x : PARK;
  int je = vd ? rr.y : PARK;
  float id = isq[dd];
  const uint8_t* xb = (const uint8_t*)xs;
  uint32_t co = (uint32_t)sub << 4;
  float ac[8];
  {
    half8 sv = *(const half8*)(xb + (((uint32_t)dd << 7) + co));
#pragma unroll
    for (int c = 0; c < 8; ++c) ac[c] = (float)sv[c];
  }
  jj = (jj < je) ? jj : PARK;
  while (__any(jj != PARK)) {
    int s0 = csr[jj];
    int s1 = csr[jj + 1];
    int s2 = csr[jj + 2];
    int s3 = csr[jj + 3];
    half8 v0 = *(const half8*)(xb + (((uint32_t)s0 << 7) + co));
    half8 v1 = *(const half8*)(xb + (((uint32_t)s1 << 7) + co));
    half8 v2 = *(const half8*)(xb + (((uint32_t)s2 << 7) + co));
    half8 v3 = *(const half8*)(xb + (((uint32_t)s3 << 7) + co));
    half8 sum = (v0 + v1) + (v2 + v3);
#pragma unroll
    for (int c = 0; c < 8; ++c) ac[c] += (float)sum[c];
    jj += 4;
    jj = (jj < je) ? jj : PARK;
  }
  {
    half8 ah;
#pragma unroll
    for (int c = 0; c < 8; ++c) ah[c] = (half_t)ac[c];
    *(half8*)&exh[li][sub * 8] = ah;
    if (sub == 0) idv[li] = id;
  }
  __syncthreads();

  int w = tid >> 6;
  int lr = lane & 15;
  int lk = lane >> 4;
  long d0b = (long)blockIdx.x * 32;
#pragma unroll
  for (int t2 = 0; t2 < 2; ++t2) {
    int tile = w * 2 + t2;
    int mt = tile >> 2;
    int nt = tile & 3;
    f32x4 acc = {0.f, 0.f, 0.f, 0.f};
#pragma unroll
    for (int ks = 0; ks < 2; ++ks) {
      half8 a = *(const half8*)&exh[mt * 16 + lr][ks * 32 + lk * 8];
      half8 b = *(const half8*)&Wt[nt * 16 + lr][ks * 32 + lk * 8];
      acc = __builtin_amdgcn_mfma_f32_16x16x32_f16(a, b, acc, 0, 0, 0);
    }
    float bv = bias[nt * 16 + lr];
#pragma unroll
    for (int j = 0; j < 4; ++j) {
      int nl = mt * 16 + lk * 4 + j;
      long dn = d0b + nl;
      if (dn < N) {
        float id2 = idv[nl];
        float m = scale_out ? id2 : 1.f;
        float r = fmaxf(fmaf(acc[j], id2, bv), 0.f) * m;
        out[dn * 64 + nt * 16 + lr] = (half_t)r;
      }
    }
  }
}

// ---------------- graph segment offsets from sorted batch_idx ----------------
__global__ void seg_offsets(const int* __restrict__ batch, int* __restrict__ off, int N, int G) {
  int i = blockIdx.x * blockDim.x + threadIdx.x;
  if (i >= N) return;
  int b = batch[i];
  if (i == 0) {
    for (int g = 0; g <= b; ++g) off[g] = 0;
  } else {
    int pb = batch[i - 1];
    for (int g = pb + 1; g <= b; ++g) off[g] = i;
  }
  if (i == N - 1) {
    for (int g = b + 1; g <= G; ++g) off[g] = N;
  }
}

// ------- mean pool over fp16 rows: lane = half8 (16B), 8 row-parities/wave -------
__global__ void pool_mean(const half_t* __restrict__ e2, const int* __restrict__ off,
                          float* __restrict__ ge, int G) {
  int lane = threadIdx.x & 63;
  int wid = (blockIdx.x * blockDim.x + threadIdx.x) >> 6;
  int nw = (gridDim.x * blockDim.x) >> 6;
  int c8 = lane & 7;
  int rp = lane >> 3;
  for (int g = wid; g < G; g += nw) {
    int s = off[g];
    int e = off[g + 1];
    float acc[8];
#pragma unroll
    for (int c = 0; c < 8; ++c) acc[c] = 0.f;
    for (int n = s + rp; n < e; n += 8) {
      half8 v = *(const half8*)&e2[(long)n * 64 + c8 * 8];
#pragma unroll
      for (int c = 0; c < 8; ++c) acc[c] += (float)v[c];
    }
#pragma unroll
    for (int c = 0; c < 8; ++c) {
      acc[c] += __shfl_xor(acc[c], 8, 64);
      acc[c] += __shfl_xor(acc[c], 16, 64);
      acc[c] += __shfl_xor(acc[c], 32, 64);
    }
    if (rp == 0) {
      float inv = 1.f / fmaxf((float)(e - s), 1.f);
      float4 lo = make_float4(acc[0] * inv, acc[1] * inv, acc[2] * inv, acc[3] * inv);
      float4 hi = make_float4(acc[4] * inv, acc[5] * inv, acc[6] * inv, acc[7] * inv);
      *(float4*)&ge[(long)g * 64 + c8 * 8] = lo;
      *(float4*)&ge[(long)g * 64 + c8 * 8 + 4] = hi;
    }
  }
}

// ------- pair MLP via MFMA: 256 pairs/block; feat & Wr1^T staged fp16 in LDS -------
#define PPB 256
__global__ __launch_bounds__(256) void pair_mlp(const float* __restrict__ ge,
                                                const int* __restrict__ dp,
                                                const float* __restrict__ Wr1,
                                                const float* __restrict__ br1,
                                                const float* __restrict__ Wr2,
                                                const float* __restrict__ br2,
                                                float* __restrict__ out, int P) {
  __shared__ half_t Wt[256][136];  // [hidden j][k] fp16 (~69.6 KB)
  __shared__ half_t ft[PPB][136];  // [pair][k] fp16 (~69.6 KB)
  int tid = threadIdx.x;
  for (int idx = tid; idx < 128 * 256; idx += 256) {
    int k = idx >> 8;
    int j = idx & 255;
    Wt[j][k] = (half_t)Wr1[idx];
  }
  int base = blockIdx.x * PPB;
  {
    int pp = base + tid;
    bool v = pp < P;
    int ga = v ? dp[pp] : 0;
    int gb = v ? dp[P + pp] : 0;
#pragma unroll
    for (int h = 0; h < 8; ++h) {
      const float* srow = (h < 4) ? &ge[(long)ga * 64 + h * 16] : &ge[(long)gb * 64 + (h - 4) * 16];
      float4 a0 = *(const float4*)&srow[0];
      float4 a1 = *(const float4*)&srow[4];
      float4 a2 = *(const float4*)&srow[8];
      float4 a3 = *(const float4*)&srow[12];
      half8 h0, h1;
      h0[0] = (half_t)a0.x; h0[1] = (half_t)a0.y; h0[2] = (half_t)a0.z; h0[3] = (half_t)a0.w;
      h0[4] = (half_t)a1.x; h0[5] = (half_t)a1.y; h0[6] = (half_t)a1.z; h0[7] = (half_t)a1.w;
      h1[0] = (half_t)a2.x; h1[1] = (half_t)a2.y; h1[2] = (half_t)a2.z; h1[3] = (half_t)a2.w;
      h1[4] = (half_t)a3.x; h1[5] = (half_t)a3.y; h1[6] = (half_t)a3.z; h1[7] = (half_t)a3.w;
      *(half8*)&ft[tid][h * 16] = h0;
      *(half8*)&ft[tid][h * 16 + 8] = h1;
    }
  }
  __syncthreads();

  int w = tid >> 6;
  int lane = tid & 63;
  int lr = lane & 15;
  int lk = lane >> 4;
  float b1v[16], w2v[16];
#pragma unroll
  for (int nt = 0; nt < 16; ++nt) {
    b1v[nt] = br1[nt * 16 + lr];
    w2v[nt] = Wr2[nt * 16 + lr];
  }
  float br2v = br2[0];
#pragma unroll
  for (int m4 = 0; m4 < 4; ++m4) {
    int mt = w * 4 + m4;
    float ps0 = 0.f, ps1 = 0.f, ps2 = 0.f, ps3 = 0.f;
#pragma unroll
    for (int nt = 0; nt < 16; ++nt) {
      f32x4 acc = {0.f, 0.f, 0.f, 0.f};
#pragma unroll
      for (int ks = 0; ks < 4; ++ks) {
        half8 a = *(const half8*)&ft[mt * 16 + lr][ks * 32 + lk * 8];
        half8 b = *(const half8*)&Wt[nt * 16 + lr][ks * 32 + lk * 8];
        acc = __builtin_amdgcn_mfma_f32_16x16x32_f16(a, b, acc, 0, 0, 0);
      }
      ps0 += fmaxf(acc[0] + b1v[nt], 0.f) * w2v[nt];
      ps1 += fmaxf(acc[1] + b1v[nt], 0.f) * w2v[nt];
      ps2 += fmaxf(acc[2] + b1v[nt], 0.f) * w2v[nt];
      ps3 += fmaxf(acc[3] + b1v[nt], 0.f) * w2v[nt];
    }
#pragma unroll
    for (int o = 1; o < 16; o <<= 1) {
      ps0 += __shfl_xor(ps0, o, 64);
      ps1 += __shfl_xor(ps1, o, 64);
      ps2 += __shfl_xor(ps2, o, 64);
      ps3 += __shfl_xor(ps3, o, 64);
    }
    if (lr == 0) {
      int prow = mt * 16 + lk * 4;
      int pp = base + prow;
      if (pp + 0 < P) out[pp + 0] = ps0 + br2v;
      if (pp + 1 < P) out[pp + 1] = ps1 + br2v;
      if (pp + 2 < P) out[pp + 2] = ps2 + br2v;
      if (pp + 3 < P) out[pp + 3] = ps3 + br2v;
    }
  }
}

extern "C" void kernel_launch(void* const* d_in, const int* in_sizes, int n_in,
                              void* d_out, int out_size, void* d_ws, size_t ws_size,
                              hipStream_t stream) {
  const float* x = (const float*)d_in[0];
  const int* ei = (const int*)d_in[1];
  const int* batch = (const int*)d_in[2];
  const int* dp = (const int*)d_in[3];
  const float* W1 = (const float*)d_in[4];
  const float* b1 = (const float*)d_in[5];
  const float* W2 = (const float*)d_in[6];
  const float* b2 = (const float*)d_in[7];
  const float* Wr1 = (const float*)d_in[8];
  const float* br1 = (const float*)d_in[9];
  const float* Wr2 = (const float*)d_in[10];
  const float* br2 = (const float*)d_in[11];
  float* out = (float*)d_out;

  int N = in_sizes[0] / 64;
  int E = in_sizes[1] / 2;
  int P = in_sizes[3] / 2;
  int G = N_GRAPHS;
  const int* src = ei;
  const int* dstp = ei + E;

  int nbuck = (N + 1023) >> 10;  // <= 512
  long M = (long)nbuck * NBLK;
  int PARK = E + 3072 * nbuck;   // start of parking region in padded csr space

  char* ws = (char*)d_ws;
  size_t o = 0;
  auto alloc = [&](size_t bytes) {
    void* p = ws + o;
    o += (bytes + 255) & ~(size_t)255;
    return p;
  };
  float* isq = (float*)alloc((size_t)N * 4);
  int2* rsp = (int2*)alloc((size_t)N * 8);
  int* bsum = (int*)alloc(1024 * 4);
  int* goff = (int*)alloc((size_t)(G + 1) * 4);
  int* bcnt = (int*)alloc((size_t)(M + 1) * 4);
  int* sed = (int*)alloc((size_t)E * 4);
  int* csr = (int*)alloc((size_t)(PARK + 80) * 4);
  half_t* xs1 = (half_t*)alloc((size_t)(N + 1) * 64 * 2);
  half_t* xs2 = (half_t*)alloc((size_t)(N + 1) * 64 * 2);
  half_t* abuf = (half_t*)alloc((size_t)N * 64 * 2);
  float* ge = (float*)alloc((size_t)G * 64 * 4);

  // --- CSR build, atomic-free at global scope ---
  bucket_hist<<<NBLK, 256, 0, stream>>>(dstp, bcnt, E, nbuck);
  int nbA = (int)((M + SCAN_CHUNK - 1) / SCAN_CHUNK);
  scan1<<<nbA, 256, 0, stream>>>(bcnt, bcnt, bsum, (int)M);  // in-place exclusive scan
  scan2<<<1, 256, 0, stream>>>(bsum, nbA);
  scan3<<<(int)((M + 1 + 255) / 256), 256, 0, stream>>>(bcnt, bsum, (int)(M + 1));
  bucket_scatter<<<NBLK, 256, 0, stream>>>(src, dstp, bcnt, sed, E, nbuck);
  node_csr<<<nbuck, 256, 0, stream>>>(sed, bcnt, rsp, isq, csr, E, nbuck, N, PARK);
  seg_offsets<<<(N + 255) / 256, 256, 0, stream>>>(batch, goff, N, G);

  long nocts = (long)N * 8;
  int gblocks = (N + 31) / 32;  // 4 waves/block, 8 dst/wave, 32 nodes/block
  // xs1 = x * isq (fp16); also zeroes sentinel rows of xs1/xs2
  scale_cast<<<(int)((nocts + 255) / 256), 256, 0, stream>>>(x, isq, xs1, xs2, nocts, N);
  // conv1: gather xs1, MFMA @W1 epilogue, out xs2 = relu1*isq (fp16)
  gather_fused<<<gblocks, 256, 0, stream>>>(xs1, csr, rsp, isq, W1, b1, xs2, N, PARK, 1);
  // conv2: gather xs2, MFMA @W2 epilogue, out abuf = relu2 (fp16)
  gather_fused<<<gblocks, 256, 0, stream>>>(xs2, csr, rsp, isq, W2, b2, abuf, N, PARK, 0);
  // pool
  pool_mean<<<2048, 256, 0, stream>>>(abuf, goff, ge, G);
  // pair MLP (MFMA)
  pair_mlp<<<(P + PPB - 1) / PPB, 256, 0, stream>>>(ge, dp, Wr1, br1, Wr2, br2, out, P);
}